// Round 4
// baseline (306.715 us; speedup 1.0000x reference)
//
#include <hip/hip_runtime.h>

#define LSEQ 4096
#define DMODEL 1024
#define HTOT 16
#define NAR 8
#define DHEAD 64
#define QKVS 3072  // fused QKV row stride

typedef unsigned short u16;
typedef unsigned int u32;
typedef __attribute__((ext_vector_type(8))) short bf16x8;
typedef __attribute__((ext_vector_type(4))) short bf16x4;
typedef __attribute__((ext_vector_type(4))) float f32x4;
typedef __attribute__((ext_vector_type(4))) unsigned int u32x4;

typedef __attribute__((address_space(1))) void gvoid;
typedef __attribute__((address_space(3))) void lvoid;

__device__ __forceinline__ void cp16(const void* g, void* l) {
    // async global->LDS, 16B per lane; LDS dest = wave-uniform base + lane*16
    __builtin_amdgcn_global_load_lds((gvoid*)(void*)g, (lvoid*)l, 16, 0, 0);
}

__device__ __forceinline__ float bfs(u16 v) { return __uint_as_float((u32)v << 16); }
// round-to-nearest-even fp32 -> bf16
__device__ __forceinline__ u16 f2bf(float f) {
    u32 x = __float_as_uint(f);
    return (u16)((x + 0x7fffu + ((x >> 16) & 1u)) >> 16);
}
// truncation-pack two fp32 -> packed bf16x2 (1 v_perm_b32)
__device__ __forceinline__ u32 packtr(float lo, float hi) {
    return __builtin_amdgcn_perm(__float_as_uint(hi), __float_as_uint(lo), 0x07060302u);
}

// ---------------------------------------------------------------------------
// Fused transpose of Wq/Wk/Wv: 1024x1024 fp32 -> bf16 (D = S^T), z selects.
// ---------------------------------------------------------------------------
__global__ __launch_bounds__(256) void transp_cvt3(
    const float* __restrict__ Wq, const float* __restrict__ Wk,
    const float* __restrict__ Wv, u16* __restrict__ D)
{
    __shared__ u16 T[64][72];
    const float* S = (blockIdx.z == 0) ? Wq : ((blockIdx.z == 1) ? Wk : Wv);
    u16* Dz = D + (size_t)blockIdx.z * 1024 * 1024;
    const int tid = threadIdx.x;
    const int bx = blockIdx.x, by = blockIdx.y;
#pragma unroll
    for (int i = 0; i < 4; ++i) {
        int id = tid + i * 256;
        int fr = id >> 4, fc = id & 15;
        float4 v = *(const float4*)(S + (size_t)(by * 64 + fr) * 1024 + bx * 64 + fc * 4);
        T[fc * 4 + 0][fr] = f2bf(v.x);
        T[fc * 4 + 1][fr] = f2bf(v.y);
        T[fc * 4 + 2][fr] = f2bf(v.z);
        T[fc * 4 + 3][fr] = f2bf(v.w);
    }
    __syncthreads();
#pragma unroll
    for (int i = 0; i < 2; ++i) {
        int id = tid + i * 256;
        int c = id >> 3, g = id & 7;
        *(uint4*)(Dz + (size_t)(bx * 64 + c) * 1024 + by * 64 + g * 8) = *(const uint4*)&T[c][g * 8];
    }
}

// single-matrix version for Wo
__global__ __launch_bounds__(256) void transp_cvt(
    const float* __restrict__ S, u16* __restrict__ D)
{
    __shared__ u16 T[64][72];
    const int tid = threadIdx.x;
    const int bx = blockIdx.x, by = blockIdx.y;
#pragma unroll
    for (int i = 0; i < 4; ++i) {
        int id = tid + i * 256;
        int fr = id >> 4, fc = id & 15;
        float4 v = *(const float4*)(S + (size_t)(by * 64 + fr) * 1024 + bx * 64 + fc * 4);
        T[fc * 4 + 0][fr] = f2bf(v.x);
        T[fc * 4 + 1][fr] = f2bf(v.y);
        T[fc * 4 + 2][fr] = f2bf(v.z);
        T[fc * 4 + 3][fr] = f2bf(v.w);
    }
    __syncthreads();
#pragma unroll
    for (int i = 0; i < 2; ++i) {
        int id = tid + i * 256;
        int c = id >> 3, g = id & 7;
        *(uint4*)(D + (size_t)(bx * 64 + c) * 1024 + by * 64 + g * 8) = *(const uint4*)&T[c][g * 8];
    }
}

// ---------------------------------------------------------------------------
// QKV = X @ [Wq|Wk|Wv] + FUSED RoPE epilogue. A fp32 (trunc-packed to bf16),
// Bt bf16 k-major, C bf16. 128x128 tile, BK=32, dbuf LDS, one barrier/K-step.
// ---------------------------------------------------------------------------
__global__ __launch_bounds__(256) void gemm_qkv(
    const float* __restrict__ A, const u16* __restrict__ Bt, u16* __restrict__ C)
{
    __shared__ u16 As[2][128][40];
    __shared__ u16 Bs[2][128][32];
    const int tid = threadIdx.x;
    const int lane = tid & 63, w = tid >> 6;
    const int col = lane & 15, quad = lane >> 4;
    const int bm = blockIdx.y << 7, bn = blockIdx.x << 7;
    const int wm = (w & 1) << 6, wn = (w >> 1) << 6;
    const int sr = lane >> 2, sc = (lane & 3) << 3;
    const int ar0 = tid >> 2, ag = (tid & 3) << 3;
    const f32x4 zero = {0.f, 0.f, 0.f, 0.f};
    f32x4 acc[4][4];
#pragma unroll
    for (int i = 0; i < 4; ++i)
#pragma unroll
        for (int j = 0; j < 4; ++j) acc[i][j] = zero;

    // prologue: stage k0=0 into buf 0
    {
#pragma unroll
        for (int i = 0; i < 2; ++i)
            cp16(Bt + (size_t)(bn + w * 32 + i * 16 + sr) * 1024 + sc, &Bs[0][w * 32 + i * 16][0]);
#pragma unroll
        for (int it = 0; it < 2; ++it) {
            const float* ap = A + (size_t)(bm + ar0 + it * 64) * 1024 + ag;
            float4 a0 = *(const float4*)ap;
            float4 a1 = *(const float4*)(ap + 4);
            uint4 pk;
            pk.x = packtr(a0.x, a0.y); pk.y = packtr(a0.z, a0.w);
            pk.z = packtr(a1.x, a1.y); pk.w = packtr(a1.z, a1.w);
            *(uint4*)&As[0][ar0 + it * 64][ag] = pk;
        }
    }

    for (int kc = 0; kc < 32; ++kc) {
        const int cur = kc & 1, nxt = cur ^ 1;
        __syncthreads();
        const bool pre = (kc + 1 < 32);
        float4 a0[2], a1[2];
        if (pre) {
            const int k1 = (kc + 1) * 32;
#pragma unroll
            for (int i = 0; i < 2; ++i)
                cp16(Bt + (size_t)(bn + w * 32 + i * 16 + sr) * 1024 + k1 + sc,
                     &Bs[nxt][w * 32 + i * 16][0]);
#pragma unroll
            for (int it = 0; it < 2; ++it) {
                const float* ap = A + (size_t)(bm + ar0 + it * 64) * 1024 + k1 + ag;
                a0[it] = *(const float4*)ap;
                a1[it] = *(const float4*)(ap + 4);
            }
        }
        bf16x8 af[4], bfr[4];
#pragma unroll
        for (int i = 0; i < 4; ++i) af[i] = *(const bf16x8*)&As[cur][wm + i * 16 + col][quad * 8];
#pragma unroll
        for (int j = 0; j < 4; ++j) bfr[j] = *(const bf16x8*)&Bs[cur][wn + j * 16 + col][quad * 8];
#pragma unroll
        for (int i = 0; i < 4; ++i)
#pragma unroll
            for (int j = 0; j < 4; ++j)
                acc[i][j] = __builtin_amdgcn_mfma_f32_16x16x32_bf16(af[i], bfr[j], acc[i][j], 0, 0, 0);
        if (pre) {
#pragma unroll
            for (int it = 0; it < 2; ++it) {
                uint4 pk;
                pk.x = packtr(a0[it].x, a0[it].y); pk.y = packtr(a0[it].z, a0[it].w);
                pk.z = packtr(a1[it].x, a1[it].y); pk.w = packtr(a1[it].z, a1[it].w);
                *(uint4*)&As[nxt][ar0 + it * 64][ag] = pk;
            }
        }
    }

    // fused RoPE epilogue (Q and K blocks only)
    if (blockIdx.x < 16) {
        const float scale = (blockIdx.x < 8) ? 0.18033688011112042f : 1.0f;  // Q: (1/8)*log2e
        const float inv0 = __expf((float)col * -0.2878231366242557f);         // irope = col
        const float inv1 = __expf((float)(16 + col) * -0.2878231366242557f);  // irope = 16+col
#pragma unroll
        for (int i = 0; i < 4; ++i)
#pragma unroll
            for (int r = 0; r < 4; ++r) {
                const float t = (float)(bm + wm + i * 16 + quad * 4 + r);
                float s0, c0, s1, c1;
                __sincosf(t * inv0, &s0, &c0);
                __sincosf(t * inv1, &s1, &c1);
                float a0 = acc[i][0][r], b0 = acc[i][2][r];
                acc[i][0][r] = (a0 * c0 - b0 * s0) * scale;
                acc[i][2][r] = (b0 * c0 + a0 * s0) * scale;
                float a1 = acc[i][1][r], b1 = acc[i][3][r];
                acc[i][1][r] = (a1 * c1 - b1 * s1) * scale;
                acc[i][3][r] = (b1 * c1 + a1 * s1) * scale;
            }
    }
#pragma unroll
    for (int i = 0; i < 4; ++i)
#pragma unroll
        for (int j = 0; j < 4; ++j)
#pragma unroll
            for (int r = 0; r < 4; ++r)
                C[(size_t)(bm + wm + i * 16 + quad * 4 + r) * QKVS + bn + wn + j * 16 + col] =
                    f2bf(acc[i][j][r]);
}

// ---------------------------------------------------------------------------
// out = AO @ Wot^T  (both bf16 k-major, C fp32). Double-buffered, one barrier
// per K-step, both operands via async global_load_lds.
// ---------------------------------------------------------------------------
__global__ __launch_bounds__(256) void gemm_out(
    const u16* __restrict__ A, const u16* __restrict__ Bt, float* __restrict__ C)
{
    __shared__ u16 As[2][128][32];
    __shared__ u16 Bs[2][128][32];
    const int tid = threadIdx.x;
    const int lane = tid & 63, w = tid >> 6;
    const int col = lane & 15, quad = lane >> 4;
    const int bm = blockIdx.y << 7, bn = blockIdx.x << 7;
    const int wm = (w & 1) << 6, wn = (w >> 1) << 6;
    const int sr = lane >> 2, sc = (lane & 3) << 3;
    const f32x4 zero = {0.f, 0.f, 0.f, 0.f};
    f32x4 acc[4][4];
#pragma unroll
    for (int i = 0; i < 4; ++i)
#pragma unroll
        for (int j = 0; j < 4; ++j) acc[i][j] = zero;

#pragma unroll
    for (int i = 0; i < 2; ++i) {
        const int r0 = w * 32 + i * 16;
        cp16(A  + (size_t)(bm + r0 + sr) * 1024 + sc, &As[0][r0][0]);
        cp16(Bt + (size_t)(bn + r0 + sr) * 1024 + sc, &Bs[0][r0][0]);
    }

    for (int kc = 0; kc < 32; ++kc) {
        const int cur = kc & 1, nxt = cur ^ 1;
        __syncthreads();
        if (kc + 1 < 32) {
            const int k1 = (kc + 1) * 32;
#pragma unroll
            for (int i = 0; i < 2; ++i) {
                const int r0 = w * 32 + i * 16;
                cp16(A  + (size_t)(bm + r0 + sr) * 1024 + k1 + sc, &As[nxt][r0][0]);
                cp16(Bt + (size_t)(bn + r0 + sr) * 1024 + k1 + sc, &Bs[nxt][r0][0]);
            }
        }
        bf16x8 af[4], bfr[4];
#pragma unroll
        for (int i = 0; i < 4; ++i) af[i] = *(const bf16x8*)&As[cur][wm + i * 16 + col][quad * 8];
#pragma unroll
        for (int j = 0; j < 4; ++j) bfr[j] = *(const bf16x8*)&Bs[cur][wn + j * 16 + col][quad * 8];
#pragma unroll
        for (int i = 0; i < 4; ++i)
#pragma unroll
            for (int j = 0; j < 4; ++j)
                acc[i][j] = __builtin_amdgcn_mfma_f32_16x16x32_bf16(af[i], bfr[j], acc[i][j], 0, 0, 0);
    }
#pragma unroll
    for (int i = 0; i < 4; ++i)
#pragma unroll
        for (int j = 0; j < 4; ++j)
#pragma unroll
            for (int r = 0; r < 4; ++r)
                C[(size_t)(bm + wm + i * 16 + quad * 4 + r) * 1024 + bn + wn + j * 16 + col] =
                    acc[i][j][r];
}

// ---------------------------------------------------------------------------
// scratch zero: OP [1024][4096] f32 (in d_out) + l [16][4096] f32 (in ws)
// ---------------------------------------------------------------------------
__global__ __launch_bounds__(256) void zero_scratch(float* __restrict__ op, float* __restrict__ lb)
{
    const int i = blockIdx.x * 256 + threadIdx.x;
    const float4 z = {0.f, 0.f, 0.f, 0.f};
    if (i < 1024 * 1024) *(float4*)(op + (size_t)i * 4) = z;
    if (i < 16 * 4096 / 4) *(float4*)(lb + (size_t)i * 4) = z;
}

// copy l out of the region finalize will overwrite
__global__ __launch_bounds__(256) void copy_l(const float* __restrict__ src, float* __restrict__ dst)
{
    const int i = blockIdx.x * 256 + threadIdx.x;
    if (i < 16 * 4096) dst[i] = src[i];
}

// AO[q][dh] = bf16( OP[dh][q] / l[dh>>6][q] ), dh = h*64+d
__global__ __launch_bounds__(256) void finalize_attn(
    const float* __restrict__ OP, const float* __restrict__ lb, u16* __restrict__ AO)
{
    const int id = blockIdx.x * 256 + threadIdx.x;   // 4096 * 128
    const int q = id >> 7, g = id & 127;
    const int dh0 = g * 8;
    const float invl = 1.f / lb[(dh0 >> 6) * 4096 + q];
    u32 pk[4];
#pragma unroll
    for (int k = 0; k < 4; ++k) {
        float lo = OP[(size_t)(dh0 + 2 * k) * 4096 + q] * invl;
        float hi = OP[(size_t)(dh0 + 2 * k + 1) * 4096 + q] * invl;
        pk[k] = ((u32)f2bf(lo)) | (((u32)f2bf(hi)) << 16);
    }
    uint4 o; o.x = pk[0]; o.y = pk[1]; o.z = pk[2]; o.w = pk[3];
    *(uint4*)(AO + (size_t)q * 1024 + dh0) = o;
}

// ---------------------------------------------------------------------------
// MFMA flash attention v8 — v7 pipeline + KV-range split for balance:
//  * Makespan was critical-path-bound: the longest block (32 chunks) at
//    2-resident pace = whole-kernel duration. Every (h, q-tile) is now split
//    into KV-parts of <=8 chunks; grid 2048 >> 512 resident -> dynamic
//    backfill balances CUs; longest chain 32 -> 8 chunks.
//  * Softmax is max-free (exp2 + l-norm), so partial (O, l) over a KV range
//    is ADDITIVE: each block atomicAdds fp32 O-partials into OP[dh][q]
//    (q-contiguous -> quad atomics coalesce to 64B) and l into lb[h][q].
//    finalize_attn divides and packs bf16 into AO.
//  * Per-chunk pipeline (cperm Vt, K=32 PV, ks-outer S, setprio) unchanged.
// ---------------------------------------------------------------------------
__global__ __launch_bounds__(256) void attn_mfma(
    const u16* __restrict__ QKV, float* __restrict__ OP, float* __restrict__ lb)
{
    __shared__ u16 Ks[2][128][64];   // [key][dim], unpadded, XOR-swizzled 16B blocks
    __shared__ u16 Vt[2][64][136];   // [dim][cperm(key)] column-permuted + 8-u16 pad
    const int bid = blockIdx.x;
    int h, qt, c0, c1;
    if (bid < 1024) {                      // diff: 4 parts x 8 chunks
        h = 8 + (bid & 7); qt = (bid >> 3) & 31;
        c0 = (bid >> 8) * 8; c1 = c0 + 8;
    } else {                               // causal: parts of <=8 chunks, desc qt
        const int i = bid - 1024;
        h = i & 7; qt = 31 - ((i >> 3) & 31);
        c0 = (i >> 8) * 8;
        if (c0 > qt) return;               // empty part (uniform exit, pre-barrier)
        c1 = (c0 + 8 < qt + 1) ? (c0 + 8) : (qt + 1);
    }
    const bool causal = (h < NAR);
    const int tid = threadIdx.x;
    const int w = tid >> 6, lane = tid & 63;
    const int col = lane & 15, quad = lane >> 4;
    const int qb = qt * 128;
    const int qr0 = qb + w * 32 + col;
    const int qr1 = qr0 + 16;
    // column-permuted position of key a=2*lane (a's pair b=a+1 sits at cva+1)
    const int cva = ((lane >> 1) & 3) * 32 + (lane >> 3) * 4 + (lane & 1) * 2;

    // hoisted Q B-frags (rope'd, pre-scaled by 0.125*log2e in gemm_qkv)
    bf16x8 qf[2][2];
#pragma unroll
    for (int s = 0; s < 2; ++s)
#pragma unroll
        for (int ks = 0; ks < 2; ++ks)
            qf[s][ks] = *(const bf16x8*)(QKV + (size_t)(qr0 + s * 16) * QKVS +
                                         h * DHEAD + ks * 32 + quad * 8);

    bf16x8 ones8;
#pragma unroll
    for (int i = 0; i < 8; ++i) ones8[i] = (short)0x3F80;

    const f32x4 zero = {0.f, 0.f, 0.f, 0.f};
    f32x4 O[2][5];  // [set][nd] O^T tiles (d = nd*16+quad*4+r, q = col); nd=4 = l
#pragma unroll
    for (int s = 0; s < 2; ++s)
#pragma unroll
        for (int nd = 0; nd < 5; ++nd) O[s][nd] = zero;

    const int krow = lane >> 3;
    const int kcb = (lane & 7) ^ krow;
    const u16* kbase = QKV + (size_t)krow * QKVS + 1024 + h * DHEAD + kcb * 8;
    const u16* vbase = QKV + (size_t)(lane * 2) * QKVS + 2048 + h * DHEAD + w * 16;

    u32x4 vA0, vA1, vB0, vB1;   // pending V(ch) for this iter's Vt write
    bf16x8 pf8[2][4];           // P(ch) frags: pf8[s][tp] = keys 32tp..32tp+31 (permuted)

#define VT_WRITE(CUR)                                                                              \
    _Pragma("unroll")                                                                              \
    for (int j = 0; j < 4; ++j) {                                                                  \
        *(u32*)&Vt[CUR][w * 16 + 2 * j][cva]         = __builtin_amdgcn_perm(vB0[j], vA0[j], 0x05040100u); \
        *(u32*)&Vt[CUR][w * 16 + 2 * j + 1][cva]     = __builtin_amdgcn_perm(vB0[j], vA0[j], 0x07060302u); \
        *(u32*)&Vt[CUR][w * 16 + 8 + 2 * j][cva]     = __builtin_amdgcn_perm(vB1[j], vA1[j], 0x05040100u); \
        *(u32*)&Vt[CUR][w * 16 + 8 + 2 * j + 1][cva] = __builtin_amdgcn_perm(vB1[j], vA1[j], 0x07060302u); \
    }

// PV burst over Vt[PRV] at K=32: tp-outer, l-row folded in -> acc reuse
// distance 10; 40 full-rate MFMAs.
#define PV_STEP(PRV)                                                                               \
    {                                                                                              \
        __builtin_amdgcn_s_setprio(1);                                                             \
        _Pragma("unroll")                                                                          \
        for (int tp = 0; tp < 4; ++tp) {                                                           \
            bf16x8 vv[4];                                                                          \
            _Pragma("unroll")                                                                      \
            for (int nd = 0; nd < 4; ++nd)                                                         \
                vv[nd] = *(const bf16x8*)&Vt[PRV][nd * 16 + col][quad * 32 + tp * 8];              \
            _Pragma("unroll")                                                                      \
            for (int nd = 0; nd < 4; ++nd) {                                                       \
                O[0][nd] = __builtin_amdgcn_mfma_f32_16x16x32_bf16(vv[nd], pf8[0][tp], O[0][nd], 0, 0, 0); \
                O[1][nd] = __builtin_amdgcn_mfma_f32_16x16x32_bf16(vv[nd], pf8[1][tp], O[1][nd], 0, 0, 0); \
            }                                                                                      \
            O[0][4] = __builtin_amdgcn_mfma_f32_16x16x32_bf16(ones8, pf8[0][tp], O[0][4], 0, 0, 0); \
            O[1][4] = __builtin_amdgcn_mfma_f32_16x16x32_bf16(ones8, pf8[1][tp], O[1][4], 0, 0, 0); \
        }                                                                                          \
        __builtin_amdgcn_s_setprio(0);                                                             \
    }

// S(CH) + exp -> pf8. ks-outer: st[s][jj] reuse distance 8.
#define S_STEP(KBUF, CH)                                                                           \
    {                                                                                              \
        const bool mask = causal && ((CH) == qt);                                                  \
        _Pragma("unroll")                                                                          \
        for (int hf = 0; hf < 2; ++hf) {                                                           \
            f32x4 st[2][4];                                                                        \
            _Pragma("unroll")                                                                      \
            for (int s = 0; s < 2; ++s)                                                            \
                _Pragma("unroll")                                                                  \
                for (int jj = 0; jj < 4; ++jj) st[s][jj] = zero;                                   \
            __builtin_amdgcn_s_setprio(1);                                                         \
            _Pragma("unroll")                                                                      \
            for (int ks = 0; ks < 2; ++ks)                                                         \
                _Pragma("unroll")                                                                  \
                for (int jj = 0; jj < 4; ++jj) {                                                   \
                    bf16x8 kf = *(const bf16x8*)&Ks[KBUF][(hf * 4 + jj) * 16 + col]                \
                                                         [((ks * 4 + quad) ^ (col & 7)) * 8];      \
                    st[0][jj] = __builtin_amdgcn_mfma_f32_16x16x32_bf16(kf, qf[0][ks], st[0][jj], 0, 0, 0); \
                    st[1][jj] = __builtin_amdgcn_mfma_f32_16x16x32_bf16(kf, qf[1][ks], st[1][jj], 0, 0, 0); \
                }                                                                                  \
            __builtin_amdgcn_s_setprio(0);                                                         \
            if (mask) {                                                                            \
                _Pragma("unroll")                                                                  \
                for (int jj = 0; jj < 4; ++jj) {                                                   \
                    const int kk = (CH) * 128 + (hf * 4 + jj) * 16 + quad * 4;                     \
                    _Pragma("unroll")                                                              \
                    for (int r = 0; r < 4; ++r) {                                                  \
                        if (kk + r > qr0) st[0][jj][r] = -1e30f;                                   \
                        if (kk + r > qr1) st[1][jj][r] = -1e30f;                                   \
                    }                                                                              \
                }                                                                                  \
            }                                                                                      \
            _Pragma("unroll")                                                                      \
            for (int s = 0; s < 2; ++s)                                                            \
                _Pragma("unroll")                                                                  \
                for (int jj = 0; jj < 4; ++jj) {                                                   \
                    u32 plo = packtr(__builtin_amdgcn_exp2f(st[s][jj][0]),                         \
                                     __builtin_amdgcn_exp2f(st[s][jj][1]));                        \
                    u32 phi = packtr(__builtin_amdgcn_exp2f(st[s][jj][2]),                         \
                                     __builtin_amdgcn_exp2f(st[s][jj][3]));                        \
                    u32* p = (u32*)&pf8[s][0] + (hf * 4 + jj) * 2;                                 \
                    p[0] = plo; p[1] = phi;                                                        \
                }                                                                                  \
        }                                                                                          \
    }

    // ---- prologue: stage chunk c0 (c0 even -> buffer 0) ----
#pragma unroll
    for (int i = 0; i < 4; ++i)
        cp16(kbase + (size_t)(c0 * 128 + (i * 4 + w) * 8) * QKVS, &Ks[0][(i * 4 + w) * 8][0]);
    {
        const u16* vp = vbase + (size_t)c0 * 128 * QKVS;
        vA0 = *(u32x4*)(vp);
        vA1 = *(u32x4*)(vp + 8);
        vB0 = *(u32x4*)(vp + QKVS);
        vB1 = *(u32x4*)(vp + QKVS + 8);
    }
    __syncthreads();  // cp16(c0) drained
    VT_WRITE(0);
    if (c1 - c0 > 1) {  // prefetch chunk c0+1
#pragma unroll
        for (int i = 0; i < 4; ++i)
            cp16(kbase + (size_t)((c0 + 1) * 128 + (i * 4 + w) * 8) * QKVS, &Ks[1][(i * 4 + w) * 8][0]);
        const u16* vp = vbase + (size_t)(c0 + 1) * 128 * QKVS;
        vA0 = *(u32x4*)(vp);
        vA1 = *(u32x4*)(vp + 8);
        vB0 = *(u32x4*)(vp + QKVS);
        vB1 = *(u32x4*)(vp + QKVS + 8);
    }
    // S(c0) + exp -> pf8
    S_STEP(0, c0);

    // ---- main loop: PV(ch-1) + S(ch) per iteration ----
    for (int ch = c0 + 1; ch < c1; ++ch) {
        const int cur = ch & 1, prv = cur ^ 1;
        __syncthreads();  // Ks[cur] staged; Vt[prv] visible; Vt[cur] free
        VT_WRITE(cur);
        if (ch + 1 < c1) {  // prefetch chunk ch+1
            const size_t cc = (size_t)(ch + 1) * 128;
#pragma unroll
            for (int i = 0; i < 4; ++i)
                cp16(kbase + (cc + (i * 4 + w) * 8) * QKVS, &Ks[prv][(i * 4 + w) * 8][0]);
            const u16* vp = vbase + cc * QKVS;
            vA0 = *(u32x4*)(vp);
            vA1 = *(u32x4*)(vp + 8);
            vB0 = *(u32x4*)(vp + QKVS);
            vB1 = *(u32x4*)(vp + QKVS + 8);
        }
        PV_STEP(prv);
        S_STEP(cur, ch);
    }

    // ---- tail: PV(c1-1) ----
    __syncthreads();
    {
        const int prv = (c1 - 1) & 1;
        PV_STEP(prv);
    }
    // epilogue: additive fp32 partials; q = col-indexed (contiguous per quad)
#pragma unroll
    for (int s = 0; s < 2; ++s) {
        const int q = qr0 + s * 16;
#pragma unroll
        for (int nd = 0; nd < 4; ++nd)
#pragma unroll
            for (int r = 0; r < 4; ++r)
                atomicAdd(&OP[(size_t)(h * 64 + nd * 16 + quad * 4 + r) * 4096 + q], O[s][nd][r]);
        if (quad == 0) atomicAdd(&lb[h * 4096 + q], O[s][4][0]);
    }
#undef VT_WRITE
#undef PV_STEP
#undef S_STEP
}

// ---------------------------------------------------------------------------
extern "C" void kernel_launch(void* const* d_in, const int* in_sizes, int n_in,
                              void* d_out, int out_size, void* d_ws, size_t ws_size,
                              hipStream_t stream)
{
    const float* X  = (const float*)d_in[0];
    const float* Wq = (const float*)d_in[1];
    const float* Wk = (const float*)d_in[2];
    const float* Wv = (const float*)d_in[3];
    const float* Wo = (const float*)d_in[4];
    float* out = (float*)d_out;

    // ws (u16 units), liveness overlays:
    //   [0 .. 3M):       Wqkvt [3072][1024] (dead after gemm_qkv)
    //   [0 .. 4M):       AOb [4096][1024] (written by finalize, read by gemm_out)
    //   [3M .. 3M+128K): lA f32 [16][4096] (written by attn; copied out before finalize)
    //   [4M .. 16M):     QKV [4096][3072] (dead after attn) -> Wot [1024][1024] at [4M..5M)
    //   [5M .. 5M+128K): lB f32 (copy of lA, read by finalize)
    // d_out (16 MB f32): OP [1024][4096] O-partials during attn, then final out.
    u16* Wt  = (u16*)d_ws;
    u16* AOb = (u16*)d_ws;
    float* lA = (float*)((u16*)d_ws + (size_t)3 * 1024 * 1024);
    u16* QKV = (u16*)d_ws + (size_t)4 * 1024 * 1024;
    u16* Wot = QKV;
    float* lB = (float*)((u16*)d_ws + (size_t)5 * 1024 * 1024);
    float* OP = out;

    zero_scratch<<<4096, 256, 0, stream>>>(OP, lA);
    transp_cvt3<<<dim3(16, 16, 3), 256, 0, stream>>>(Wq, Wk, Wv, Wt);
    gemm_qkv<<<dim3(24, 32), 256, 0, stream>>>(X, Wt, QKV);   // rope fused in epilogue
    attn_mfma<<<2048, 256, 0, stream>>>(QKV, OP, lA);
    copy_l<<<256, 256, 0, stream>>>(lA, lB);
    transp_cvt<<<dim3(16, 16), 256, 0, stream>>>(Wo, Wot);    // QKV dead now
    finalize_attn<<<2048, 256, 0, stream>>>(OP, lB, AOb);
    gemm_out<<<dim3(8, 32), 256, 0, stream>>>(AOb, Wot, out); // overwrites OP scratch
}

// Round 5
// 245.068 us; speedup vs baseline: 1.2515x; 1.2515x over previous
//
#include <hip/hip_runtime.h>

#define LSEQ 4096
#define DMODEL 1024
#define HTOT 16
#define NAR 8
#define DHEAD 64
#define QKVS 3072  // fused QKV row stride

typedef unsigned short u16;
typedef unsigned int u32;
typedef __attribute__((ext_vector_type(8))) short bf16x8;
typedef __attribute__((ext_vector_type(4))) short bf16x4;
typedef __attribute__((ext_vector_type(4))) float f32x4;
typedef __attribute__((ext_vector_type(4))) unsigned int u32x4;

typedef __attribute__((address_space(1))) void gvoid;
typedef __attribute__((address_space(3))) void lvoid;

__device__ __forceinline__ void cp16(const void* g, void* l) {
    // async global->LDS, 16B per lane; LDS dest = wave-uniform base + lane*16
    __builtin_amdgcn_global_load_lds((gvoid*)(void*)g, (lvoid*)l, 16, 0, 0);
}

// round-to-nearest-even fp32 -> bf16
__device__ __forceinline__ u16 f2bf(float f) {
    u32 x = __float_as_uint(f);
    return (u16)((x + 0x7fffu + ((x >> 16) & 1u)) >> 16);
}
// truncation-pack two fp32 -> packed bf16x2 (1 v_perm_b32)
__device__ __forceinline__ u32 packtr(float lo, float hi) {
    return __builtin_amdgcn_perm(__float_as_uint(hi), __float_as_uint(lo), 0x07060302u);
}

// ---------------------------------------------------------------------------
// Fused transpose of Wq/Wk/Wv: 1024x1024 fp32 -> bf16 (D = S^T), z selects.
// ---------------------------------------------------------------------------
__global__ __launch_bounds__(256) void transp_cvt3(
    const float* __restrict__ Wq, const float* __restrict__ Wk,
    const float* __restrict__ Wv, u16* __restrict__ D)
{
    __shared__ u16 T[64][72];
    const float* S = (blockIdx.z == 0) ? Wq : ((blockIdx.z == 1) ? Wk : Wv);
    u16* Dz = D + (size_t)blockIdx.z * 1024 * 1024;
    const int tid = threadIdx.x;
    const int bx = blockIdx.x, by = blockIdx.y;
#pragma unroll
    for (int i = 0; i < 4; ++i) {
        int id = tid + i * 256;
        int fr = id >> 4, fc = id & 15;
        float4 v = *(const float4*)(S + (size_t)(by * 64 + fr) * 1024 + bx * 64 + fc * 4);
        T[fc * 4 + 0][fr] = f2bf(v.x);
        T[fc * 4 + 1][fr] = f2bf(v.y);
        T[fc * 4 + 2][fr] = f2bf(v.z);
        T[fc * 4 + 3][fr] = f2bf(v.w);
    }
    __syncthreads();
#pragma unroll
    for (int i = 0; i < 2; ++i) {
        int id = tid + i * 256;
        int c = id >> 3, g = id & 7;
        *(uint4*)(Dz + (size_t)(bx * 64 + c) * 1024 + by * 64 + g * 8) = *(const uint4*)&T[c][g * 8];
    }
}

// single-matrix version for Wo
__global__ __launch_bounds__(256) void transp_cvt(
    const float* __restrict__ S, u16* __restrict__ D)
{
    __shared__ u16 T[64][72];
    const int tid = threadIdx.x;
    const int bx = blockIdx.x, by = blockIdx.y;
#pragma unroll
    for (int i = 0; i < 4; ++i) {
        int id = tid + i * 256;
        int fr = id >> 4, fc = id & 15;
        float4 v = *(const float4*)(S + (size_t)(by * 64 + fr) * 1024 + bx * 64 + fc * 4);
        T[fc * 4 + 0][fr] = f2bf(v.x);
        T[fc * 4 + 1][fr] = f2bf(v.y);
        T[fc * 4 + 2][fr] = f2bf(v.z);
        T[fc * 4 + 3][fr] = f2bf(v.w);
    }
    __syncthreads();
#pragma unroll
    for (int i = 0; i < 2; ++i) {
        int id = tid + i * 256;
        int c = id >> 3, g = id & 7;
        *(uint4*)(D + (size_t)(bx * 64 + c) * 1024 + by * 64 + g * 8) = *(const uint4*)&T[c][g * 8];
    }
}

// ---------------------------------------------------------------------------
// QKV = X @ [Wq|Wk|Wv] + FUSED RoPE epilogue. A fp32 (trunc-packed to bf16),
// Bt bf16 k-major, C bf16. 128x128 tile, BK=32, dbuf LDS, one barrier/K-step.
// ---------------------------------------------------------------------------
__global__ __launch_bounds__(256) void gemm_qkv(
    const float* __restrict__ A, const u16* __restrict__ Bt, u16* __restrict__ C)
{
    __shared__ u16 As[2][128][40];
    __shared__ u16 Bs[2][128][32];
    const int tid = threadIdx.x;
    const int lane = tid & 63, w = tid >> 6;
    const int col = lane & 15, quad = lane >> 4;
    const int bm = blockIdx.y << 7, bn = blockIdx.x << 7;
    const int wm = (w & 1) << 6, wn = (w >> 1) << 6;
    const int sr = lane >> 2, sc = (lane & 3) << 3;
    const int ar0 = tid >> 2, ag = (tid & 3) << 3;
    const f32x4 zero = {0.f, 0.f, 0.f, 0.f};
    f32x4 acc[4][4];
#pragma unroll
    for (int i = 0; i < 4; ++i)
#pragma unroll
        for (int j = 0; j < 4; ++j) acc[i][j] = zero;

    // prologue: stage k0=0 into buf 0
    {
#pragma unroll
        for (int i = 0; i < 2; ++i)
            cp16(Bt + (size_t)(bn + w * 32 + i * 16 + sr) * 1024 + sc, &Bs[0][w * 32 + i * 16][0]);
#pragma unroll
        for (int it = 0; it < 2; ++it) {
            const float* ap = A + (size_t)(bm + ar0 + it * 64) * 1024 + ag;
            float4 a0 = *(const float4*)ap;
            float4 a1 = *(const float4*)(ap + 4);
            uint4 pk;
            pk.x = packtr(a0.x, a0.y); pk.y = packtr(a0.z, a0.w);
            pk.z = packtr(a1.x, a1.y); pk.w = packtr(a1.z, a1.w);
            *(uint4*)&As[0][ar0 + it * 64][ag] = pk;
        }
    }

    for (int kc = 0; kc < 32; ++kc) {
        const int cur = kc & 1, nxt = cur ^ 1;
        __syncthreads();
        const bool pre = (kc + 1 < 32);
        float4 a0[2], a1[2];
        if (pre) {
            const int k1 = (kc + 1) * 32;
#pragma unroll
            for (int i = 0; i < 2; ++i)
                cp16(Bt + (size_t)(bn + w * 32 + i * 16 + sr) * 1024 + k1 + sc,
                     &Bs[nxt][w * 32 + i * 16][0]);
#pragma unroll
            for (int it = 0; it < 2; ++it) {
                const float* ap = A + (size_t)(bm + ar0 + it * 64) * 1024 + k1 + ag;
                a0[it] = *(const float4*)ap;
                a1[it] = *(const float4*)(ap + 4);
            }
        }
        bf16x8 af[4], bfr[4];
#pragma unroll
        for (int i = 0; i < 4; ++i) af[i] = *(const bf16x8*)&As[cur][wm + i * 16 + col][quad * 8];
#pragma unroll
        for (int j = 0; j < 4; ++j) bfr[j] = *(const bf16x8*)&Bs[cur][wn + j * 16 + col][quad * 8];
#pragma unroll
        for (int i = 0; i < 4; ++i)
#pragma unroll
            for (int j = 0; j < 4; ++j)
                acc[i][j] = __builtin_amdgcn_mfma_f32_16x16x32_bf16(af[i], bfr[j], acc[i][j], 0, 0, 0);
        if (pre) {
#pragma unroll
            for (int it = 0; it < 2; ++it) {
                uint4 pk;
                pk.x = packtr(a0[it].x, a0[it].y); pk.y = packtr(a0[it].z, a0[it].w);
                pk.z = packtr(a1[it].x, a1[it].y); pk.w = packtr(a1[it].z, a1[it].w);
                *(uint4*)&As[nxt][ar0 + it * 64][ag] = pk;
            }
        }
    }

    // fused RoPE epilogue (Q and K blocks only)
    if (blockIdx.x < 16) {
        const float scale = (blockIdx.x < 8) ? 0.18033688011112042f : 1.0f;  // Q: (1/8)*log2e
        const float inv0 = __expf((float)col * -0.2878231366242557f);         // irope = col
        const float inv1 = __expf((float)(16 + col) * -0.2878231366242557f);  // irope = 16+col
#pragma unroll
        for (int i = 0; i < 4; ++i)
#pragma unroll
            for (int r = 0; r < 4; ++r) {
                const float t = (float)(bm + wm + i * 16 + quad * 4 + r);
                float s0, c0, s1, c1;
                __sincosf(t * inv0, &s0, &c0);
                __sincosf(t * inv1, &s1, &c1);
                float a0 = acc[i][0][r], b0 = acc[i][2][r];
                acc[i][0][r] = (a0 * c0 - b0 * s0) * scale;
                acc[i][2][r] = (b0 * c0 + a0 * s0) * scale;
                float a1 = acc[i][1][r], b1 = acc[i][3][r];
                acc[i][1][r] = (a1 * c1 - b1 * s1) * scale;
                acc[i][3][r] = (b1 * c1 + a1 * s1) * scale;
            }
    }
#pragma unroll
    for (int i = 0; i < 4; ++i)
#pragma unroll
        for (int j = 0; j < 4; ++j)
#pragma unroll
            for (int r = 0; r < 4; ++r)
                C[(size_t)(bm + wm + i * 16 + quad * 4 + r) * QKVS + bn + wn + j * 16 + col] =
                    f2bf(acc[i][j][r]);
}

// ---------------------------------------------------------------------------
// out = AO @ Wot^T  (both bf16 k-major, C fp32). Double-buffered, one barrier
// per K-step, both operands via async global_load_lds.
// ---------------------------------------------------------------------------
__global__ __launch_bounds__(256) void gemm_out(
    const u16* __restrict__ A, const u16* __restrict__ Bt, float* __restrict__ C)
{
    __shared__ u16 As[2][128][32];
    __shared__ u16 Bs[2][128][32];
    const int tid = threadIdx.x;
    const int lane = tid & 63, w = tid >> 6;
    const int col = lane & 15, quad = lane >> 4;
    const int bm = blockIdx.y << 7, bn = blockIdx.x << 7;
    const int wm = (w & 1) << 6, wn = (w >> 1) << 6;
    const int sr = lane >> 2, sc = (lane & 3) << 3;
    const f32x4 zero = {0.f, 0.f, 0.f, 0.f};
    f32x4 acc[4][4];
#pragma unroll
    for (int i = 0; i < 4; ++i)
#pragma unroll
        for (int j = 0; j < 4; ++j) acc[i][j] = zero;

#pragma unroll
    for (int i = 0; i < 2; ++i) {
        const int r0 = w * 32 + i * 16;
        cp16(A  + (size_t)(bm + r0 + sr) * 1024 + sc, &As[0][r0][0]);
        cp16(Bt + (size_t)(bn + r0 + sr) * 1024 + sc, &Bs[0][r0][0]);
    }

    for (int kc = 0; kc < 32; ++kc) {
        const int cur = kc & 1, nxt = cur ^ 1;
        __syncthreads();
        if (kc + 1 < 32) {
            const int k1 = (kc + 1) * 32;
#pragma unroll
            for (int i = 0; i < 2; ++i) {
                const int r0 = w * 32 + i * 16;
                cp16(A  + (size_t)(bm + r0 + sr) * 1024 + k1 + sc, &As[nxt][r0][0]);
                cp16(Bt + (size_t)(bn + r0 + sr) * 1024 + k1 + sc, &Bs[nxt][r0][0]);
            }
        }
        bf16x8 af[4], bfr[4];
#pragma unroll
        for (int i = 0; i < 4; ++i) af[i] = *(const bf16x8*)&As[cur][wm + i * 16 + col][quad * 8];
#pragma unroll
        for (int j = 0; j < 4; ++j) bfr[j] = *(const bf16x8*)&Bs[cur][wn + j * 16 + col][quad * 8];
#pragma unroll
        for (int i = 0; i < 4; ++i)
#pragma unroll
            for (int j = 0; j < 4; ++j)
                acc[i][j] = __builtin_amdgcn_mfma_f32_16x16x32_bf16(af[i], bfr[j], acc[i][j], 0, 0, 0);
    }
#pragma unroll
    for (int i = 0; i < 4; ++i)
#pragma unroll
        for (int j = 0; j < 4; ++j)
#pragma unroll
            for (int r = 0; r < 4; ++r)
                C[(size_t)(bm + wm + i * 16 + quad * 4 + r) * 1024 + bn + wn + j * 16 + col] =
                    acc[i][j][r];
}

// ---------------------------------------------------------------------------
// MFMA flash attention v9 — v7 math/layout, LDS diet for residency:
//  * Round-3 evidence: Occupancy 14.3% ~= ONE 4-wave block per CU, and
//    makespan 87.6us == 32 chunks x 6560cyc single-stream wall. LDS was
//    67584 B > 64 KiB, capping co-residency at 1 WG/CU.
//  * Vt single-buffered: Ks dbuf 32768 + Vt 17408 = 50176 B < 64 KiB
//    -> 2-3 blocks/CU; two streams/SIMD hide each other's latency.
//  * Single-Vt pipeline (2 cheap barriers/chunk):
//      barrier_a: Ks[cur]=K(ch) drained, Vt=V(ch-1) visible
//      issue cp16 K(ch+1) + vload V(ch)          (full compute phase ahead)
//      PV(ch-1) [Vt] ; S(ch) [Ks[cur]] -> pf
//      barrier_b: all PV reads done; drains loads issued above
//      VT_WRITE(V(ch))
//  * Per-chunk math unchanged from v7 (cperm Vt, K=32 PV, ks-outer S,
//    setprio). Direct AO epilogue (round-4 atomics/finalize reverted).
// ---------------------------------------------------------------------------
__global__ __launch_bounds__(256) void attn_mfma(
    const u16* __restrict__ QKV, u16* __restrict__ AO)
{
    __shared__ u16 Ks[2][128][64];   // [key][dim], unpadded, XOR-swizzled 16B blocks
    __shared__ u16 Vt[64][136];      // [dim][cperm(key)] single-buffered + 8-u16 pad
    const int bid = blockIdx.x;
    int h, qt;
    if (bid < 256) { h = 8 + (bid & 7); qt = bid >> 3; }           // diff: 32 chunks
    else { int i = bid - 256; h = i & 7; qt = 31 - (i >> 3); }     // causal desc qt
    const bool causal = (h < NAR);
    const int tid = threadIdx.x;
    const int w = tid >> 6, lane = tid & 63;
    const int col = lane & 15, quad = lane >> 4;
    const int qb = qt * 128;
    const int qr0 = qb + w * 32 + col;
    const int qr1 = qr0 + 16;
    // column-permuted position of key a=2*lane (a's pair b=a+1 sits at cva+1)
    const int cva = ((lane >> 1) & 3) * 32 + (lane >> 3) * 4 + (lane & 1) * 2;

    // hoisted Q B-frags (rope'd, pre-scaled by 0.125*log2e in gemm_qkv)
    bf16x8 qf[2][2];
#pragma unroll
    for (int s = 0; s < 2; ++s)
#pragma unroll
        for (int ks = 0; ks < 2; ++ks)
            qf[s][ks] = *(const bf16x8*)(QKV + (size_t)(qr0 + s * 16) * QKVS +
                                         h * DHEAD + ks * 32 + quad * 8);

    bf16x8 ones8;
#pragma unroll
    for (int i = 0; i < 8; ++i) ones8[i] = (short)0x3F80;

    const f32x4 zero = {0.f, 0.f, 0.f, 0.f};
    f32x4 O[2][5];  // [set][nd] O^T tiles (d = nd*16+quad*4+r, q = col); nd=4 = l
#pragma unroll
    for (int s = 0; s < 2; ++s)
#pragma unroll
        for (int nd = 0; nd < 5; ++nd) O[s][nd] = zero;

    const int nch = causal ? (qt + 1) : (LSEQ / 128);
    const int krow = lane >> 3;
    const int kcb = (lane & 7) ^ krow;
    const u16* kbase = QKV + (size_t)krow * QKVS + 1024 + h * DHEAD + kcb * 8;
    const u16* vbase = QKV + (size_t)(lane * 2) * QKVS + 2048 + h * DHEAD + w * 16;

    u32x4 vA0, vA1, vB0, vB1;   // pending V(ch) regs for end-of-iter Vt write
    bf16x8 pf8[2][4];           // P(ch) frags: pf8[s][tp] = keys 32tp..32tp+31 (permuted)

#define VT_WRITE()                                                                                 \
    _Pragma("unroll")                                                                              \
    for (int j = 0; j < 4; ++j) {                                                                  \
        *(u32*)&Vt[w * 16 + 2 * j][cva]         = __builtin_amdgcn_perm(vB0[j], vA0[j], 0x05040100u); \
        *(u32*)&Vt[w * 16 + 2 * j + 1][cva]     = __builtin_amdgcn_perm(vB0[j], vA0[j], 0x07060302u); \
        *(u32*)&Vt[w * 16 + 8 + 2 * j][cva]     = __builtin_amdgcn_perm(vB1[j], vA1[j], 0x05040100u); \
        *(u32*)&Vt[w * 16 + 8 + 2 * j + 1][cva] = __builtin_amdgcn_perm(vB1[j], vA1[j], 0x07060302u); \
    }

// PV burst over Vt at K=32: tp-outer, l-row folded in -> acc reuse distance 10.
#define PV_STEP()                                                                                  \
    {                                                                                              \
        __builtin_amdgcn_s_setprio(1);                                                             \
        _Pragma("unroll")                                                                          \
        for (int tp = 0; tp < 4; ++tp) {                                                           \
            bf16x8 vv[4];                                                                          \
            _Pragma("unroll")                                                                      \
            for (int nd = 0; nd < 4; ++nd)                                                         \
                vv[nd] = *(const bf16x8*)&Vt[nd * 16 + col][quad * 32 + tp * 8];                   \
            _Pragma("unroll")                                                                      \
            for (int nd = 0; nd < 4; ++nd) {                                                       \
                O[0][nd] = __builtin_amdgcn_mfma_f32_16x16x32_bf16(vv[nd], pf8[0][tp], O[0][nd], 0, 0, 0); \
                O[1][nd] = __builtin_amdgcn_mfma_f32_16x16x32_bf16(vv[nd], pf8[1][tp], O[1][nd], 0, 0, 0); \
            }                                                                                      \
            O[0][4] = __builtin_amdgcn_mfma_f32_16x16x32_bf16(ones8, pf8[0][tp], O[0][4], 0, 0, 0); \
            O[1][4] = __builtin_amdgcn_mfma_f32_16x16x32_bf16(ones8, pf8[1][tp], O[1][4], 0, 0, 0); \
        }                                                                                          \
        __builtin_amdgcn_s_setprio(0);                                                             \
    }

// S(CH) + exp -> pf8. ks-outer: st[s][jj] reuse distance 8.
#define S_STEP(KBUF, CH)                                                                           \
    {                                                                                              \
        const bool mask = causal && ((CH) == qt);                                                  \
        _Pragma("unroll")                                                                          \
        for (int hf = 0; hf < 2; ++hf) {                                                           \
            f32x4 st[2][4];                                                                        \
            _Pragma("unroll")                                                                      \
            for (int s = 0; s < 2; ++s)                                                            \
                _Pragma("unroll")                                                                  \
                for (int jj = 0; jj < 4; ++jj) st[s][jj] = zero;                                   \
            __builtin_amdgcn_s_setprio(1);                                                         \
            _Pragma("unroll")                                                                      \
            for (int ks = 0; ks < 2; ++ks)                                                         \
                _Pragma("unroll")                                                                  \
                for (int jj = 0; jj < 4; ++jj) {                                                   \
                    bf16x8 kf = *(const bf16x8*)&Ks[KBUF][(hf * 4 + jj) * 16 + col]                \
                                                         [((ks * 4 + quad) ^ (col & 7)) * 8];      \
                    st[0][jj] = __builtin_amdgcn_mfma_f32_16x16x32_bf16(kf, qf[0][ks], st[0][jj], 0, 0, 0); \
                    st[1][jj] = __builtin_amdgcn_mfma_f32_16x16x32_bf16(kf, qf[1][ks], st[1][jj], 0, 0, 0); \
                }                                                                                  \
            __builtin_amdgcn_s_setprio(0);                                                         \
            if (mask) {                                                                            \
                _Pragma("unroll")                                                                  \
                for (int jj = 0; jj < 4; ++jj) {                                                   \
                    const int kk = (CH) * 128 + (hf * 4 + jj) * 16 + quad * 4;                     \
                    _Pragma("unroll")                                                              \
                    for (int r = 0; r < 4; ++r) {                                                  \
                        if (kk + r > qr0) st[0][jj][r] = -1e30f;                                   \
                        if (kk + r > qr1) st[1][jj][r] = -1e30f;                                   \
                    }                                                                              \
                }                                                                                  \
            }                                                                                      \
            _Pragma("unroll")                                                                      \
            for (int s = 0; s < 2; ++s)                                                            \
                _Pragma("unroll")                                                                  \
                for (int jj = 0; jj < 4; ++jj) {                                                   \
                    u32 plo = packtr(__builtin_amdgcn_exp2f(st[s][jj][0]),                         \
                                     __builtin_amdgcn_exp2f(st[s][jj][1]));                        \
                    u32 phi = packtr(__builtin_amdgcn_exp2f(st[s][jj][2]),                         \
                                     __builtin_amdgcn_exp2f(st[s][jj][3]));                        \
                    u32* p = (u32*)&pf8[s][0] + (hf * 4 + jj) * 2;                                 \
                    p[0] = plo; p[1] = phi;                                                        \
                }                                                                                  \
        }                                                                                          \
    }

    // ---- prologue: stage chunk 0 ----
#pragma unroll
    for (int i = 0; i < 4; ++i)
        cp16(kbase + (size_t)((i * 4 + w) * 8) * QKVS, &Ks[0][(i * 4 + w) * 8][0]);
    vA0 = *(u32x4*)(vbase);
    vA1 = *(u32x4*)(vbase + 8);
    vB0 = *(u32x4*)(vbase + QKVS);
    vB1 = *(u32x4*)(vbase + QKVS + 8);
    __syncthreads();  // K(0) in LDS, V(0) in regs
    VT_WRITE();       // Vt <- V(0); visibility via barrier_a of iter 1 (or tail)
    if (nch > 1) {    // prefetch K(1); drained at barrier_a of iter 1
#pragma unroll
        for (int i = 0; i < 4; ++i)
            cp16(kbase + (size_t)(128 + (i * 4 + w) * 8) * QKVS, &Ks[1][(i * 4 + w) * 8][0]);
    }
    // S(0) + exp -> pf8
    S_STEP(0, 0);

    // ---- main loop ----
    for (int ch = 1; ch < nch; ++ch) {
        const int cur = ch & 1;
        __syncthreads();  // barrier_a: Ks[cur]=K(ch) drained; Vt=V(ch-1) visible
        if (ch + 1 < nch) {  // prefetch K(ch+1) into the buffer S(ch) is NOT reading
            const size_t c1 = (size_t)(ch + 1) * 128;
#pragma unroll
            for (int i = 0; i < 4; ++i)
                cp16(kbase + (c1 + (i * 4 + w) * 8) * QKVS, &Ks[cur ^ 1][(i * 4 + w) * 8][0]);
        }
        {   // V(ch) regs for end-of-iter Vt write
            const u16* vp = vbase + (size_t)ch * 128 * QKVS;
            vA0 = *(u32x4*)(vp);
            vA1 = *(u32x4*)(vp + 8);
            vB0 = *(u32x4*)(vp + QKVS);
            vB1 = *(u32x4*)(vp + QKVS + 8);
        }
        PV_STEP();        // P(ch-1) x V(ch-1)
        S_STEP(cur, ch);  // -> pf8 = P(ch)
        __syncthreads();  // barrier_b: all PV reads done; loads above drained
        VT_WRITE();       // Vt <- V(ch)
    }

    // ---- tail: PV(nch-1) ----
    __syncthreads();  // Vt = V(nch-1) visible (prologue write if nch==1)
    PV_STEP();

    // epilogue: l already in this lane (col=q); O^T rows d = nd*16+quad*4+r
#pragma unroll
    for (int s = 0; s < 2; ++s) {
        const float inv = 1.f / O[s][4][0];
        const int qrow = qr0 + s * 16;
#pragma unroll
        for (int nd = 0; nd < 4; ++nd) {
            ushort4 ov;
            ov.x = f2bf(O[s][nd][0] * inv);
            ov.y = f2bf(O[s][nd][1] * inv);
            ov.z = f2bf(O[s][nd][2] * inv);
            ov.w = f2bf(O[s][nd][3] * inv);
            *(ushort4*)(AO + (size_t)qrow * 1024 + h * DHEAD + nd * 16 + quad * 4) = ov;
        }
    }
#undef VT_WRITE
#undef PV_STEP
#undef S_STEP
}

// ---------------------------------------------------------------------------
extern "C" void kernel_launch(void* const* d_in, const int* in_sizes, int n_in,
                              void* d_out, int out_size, void* d_ws, size_t ws_size,
                              hipStream_t stream)
{
    const float* X  = (const float*)d_in[0];
    const float* Wq = (const float*)d_in[1];
    const float* Wk = (const float*)d_in[2];
    const float* Wv = (const float*)d_in[3];
    const float* Wo = (const float*)d_in[4];
    float* out = (float*)d_out;

    // ws (u16 units), liveness overlays:
    //   [0 .. 4M):   Wqkvt [3072][1024] (dead after gemm_qkv) -> AOb [4096][1024]
    //   [4M .. 16M): QKV [4096][3072] (dead after attn) -> Wot [1024][1024]
    u16* Wt  = (u16*)d_ws;
    u16* AOb = (u16*)d_ws;
    u16* QKV = (u16*)d_ws + (size_t)4 * 1024 * 1024;
    u16* Wot = QKV;

    transp_cvt3<<<dim3(16, 16, 3), 256, 0, stream>>>(Wq, Wk, Wv, Wt);
    gemm_qkv<<<dim3(24, 32), 256, 0, stream>>>(X, Wt, QKV);   // rope fused in epilogue
    attn_mfma<<<512, 256, 0, stream>>>(QKV, AOb);
    transp_cvt<<<dim3(16, 16), 256, 0, stream>>>(Wo, Wot);    // QKV dead now
    gemm_out<<<dim3(8, 32), 256, 0, stream>>>(AOb, Wot, out);
}